// Round 2
// baseline (402.644 us; speedup 1.0000x reference)
//
#include <hip/hip_runtime.h>
#include <hip/hip_bf16.h>

// ModalAttention fused pipeline, MI355X (gfx950).
//
// Math: attn/|global_min| followed by L2-normalize cancels any positive
// per-tensor scale (incl. /sqrt(h)) -> softmax input = s_row/||s_row||_2,
// s = q.k. No global-min reduction needed.
//
// Round 2: QKV projection rewritten as a single 256x256-tile, BK=64,
// 8-wave deep-pipelined GEMM (N=3072 = Q|K|V concat):
//  - counted vmcnt(8) (loads span barriers, prefetch distance 2 K-tiles)
//  - raw s_barrier + explicit lgkmcnt(0) (no vmcnt(0) drain per step)
//  - XOR bank swizzle (16B block b ^= row&7) on LDS tiles, applied as
//    pre-swizzled global_load_lds source + swizzled ds_read (both-sides rule)
//  - s_setprio(1) around second MFMA cluster
//  - bijective XCD-chunked block swizzle (768 % 8 == 0)

typedef __bf16 bf16x8 __attribute__((ext_vector_type(8)));
typedef float f32x4 __attribute__((ext_vector_type(4)));

struct alignas(16) US8 { unsigned short s[8]; };
struct alignas(8)  US4 { unsigned short s[4]; };

// ---------------- workspace layout (bytes) ----------------
#define WS_XB   0ull                        // data bf16  [16384][1024]  33.55MB
#define WS_WB   33554432ull                 // wq,wk,wv bf16 [3][1024][1024] 6.29MB
#define WS_Q    39845888ull                 // Q bf16 [16384][1024] 33.55MB
#define WS_K    73400320ull                 // K bf16 [16384][1024] 33.55MB
#define WS_VT   106954752ull                // V^T bf16 [32][1024][512] 33.55MB
#define WS_S    140509184ull                // S f32 [32][512][512] 33.55MB
#define WS_P    174063616ull                // P bf16 [16384][512] 16.78MB
#define WS_NEED 190840832ull
#define WS_O    WS_Q                        // O f32 [16384][1024] 67.1MB reuses Q+K

__device__ __forceinline__ unsigned short f32_to_bf16(float f) {
  unsigned int u = __builtin_bit_cast(unsigned int, f);
  u += 0x7fffu + ((u >> 16) & 1u);            // round-to-nearest-even
  return (unsigned short)(u >> 16);
}

__device__ __forceinline__ void gload_lds16(const void* g, void* lds) {
  __builtin_amdgcn_global_load_lds(
      (const __attribute__((address_space(1))) unsigned int*)g,
      (__attribute__((address_space(3))) unsigned int*)lds, 16, 0, 0);
}

__device__ __forceinline__ float wave_sum(float v) {
#pragma unroll
  for (int off = 32; off > 0; off >>= 1) v += __shfl_xor(v, off);
  return v;
}
__device__ __forceinline__ float wave_max(float v) {
#pragma unroll
  for (int off = 32; off > 0; off >>= 1) v = fmaxf(v, __shfl_xor(v, off));
  return v;
}

// ---------------- f32 -> bf16 cast ----------------
__global__ __launch_bounds__(256) void cvt_f32_bf16(const float* __restrict__ src,
                                                    unsigned short* __restrict__ dst,
                                                    int n8) {
  int i = blockIdx.x * 256 + threadIdx.x;
  if (i >= n8) return;
  const float4* sp = (const float4*)(src + (size_t)i * 8);
  float4 a = sp[0], b = sp[1];
  US8 u;
  u.s[0] = f32_to_bf16(a.x); u.s[1] = f32_to_bf16(a.y);
  u.s[2] = f32_to_bf16(a.z); u.s[3] = f32_to_bf16(a.w);
  u.s[4] = f32_to_bf16(b.x); u.s[5] = f32_to_bf16(b.y);
  u.s[6] = f32_to_bf16(b.z); u.s[7] = f32_to_bf16(b.w);
  *(US8*)(dst + (size_t)i * 8) = u;
}

// ============ QKV: 256x256 tile deep-pipelined GEMM, N=3072 ============
// M=16384, K=1024. Grid 768 blocks x 512 threads (8 waves, 2Mx4N).
// LDS: A[2 buf][256][64] + B[2 buf][256][64] bf16 = 128 KiB.
// Per-iter schedule (K-tile t, buffer cur=t&1):
//   slice0 ds_reads (12 x b128) ; 32 MFMA
//   slice1 ds_reads (12 x b128)
//   s_waitcnt lgkmcnt(0) ; s_barrier          <- all reads of cur done
//   STAGE kt t+2 -> cur (8 x global_load_lds) <- safe: everyone past barrier
//   setprio(1) ; 32 MFMA ; setprio(0)
//   s_waitcnt vmcnt(8)                        <- kt t+1's 8 loads landed
//   s_barrier
#define QKV_NT 16

__global__ __launch_bounds__(512, 2) void qkv_gemm256(
    const unsigned short* __restrict__ Xb, const unsigned short* __restrict__ Wb,
    unsigned short* __restrict__ Q, unsigned short* __restrict__ Kb,
    unsigned short* __restrict__ Vt) {
  __shared__ unsigned short sm[2][2][16384];   // [A/B][buf][256*64] 128 KiB

  const int tid = threadIdx.x;
  const int w = tid >> 6, lane = tid & 63;

  // bijective XCD-chunked swizzle: 768 blocks, 96 per XCD
  const int bid = blockIdx.x;
  const int wg = (bid & 7) * 96 + (bid >> 3);
  const int bm = wg / 12, bn = wg % 12;

  const unsigned short* Ag = Xb + (size_t)bm * 256 * 1024;
  const unsigned short* Bg = Wb + (size_t)bn * 256 * 1024;

  // staging constants: dest byte off = r*8192 + w*1024 + lane*16 (linear)
  //   -> row = r*64 + w*8 + (lane>>3), 16B-block b = lane&7
  //   source k-block = b ^ (row&7) = (lane&7) ^ (lane>>3)
  const int rowb = w * 8 + (lane >> 3);
  const int kx = (((lane & 7) ^ ((lane >> 3) & 7)) << 3);  // element offset

  // read constants (fragment: row = base + (lane&15), k = (lane>>4)*8 + ks*32)
  const int wm = w >> 2, wn = w & 3;
  const int lr = lane & 15, lk4 = lane >> 4;
  const int cswz0 = ((lk4 ^ (lr & 7)) << 4);   // swizzled byte col, slice 0
  // slice 1 col = cswz0 ^ 64  (k-block +4 toggles bit 2 of block = bit 6 byte)

  f32x4 acc[8][4] = {};

#define QKV_STAGE(buf, kt)                                                    \
  do {                                                                        \
    _Pragma("unroll") for (int r = 0; r < 4; ++r) {                           \
      gload_lds16(Ag + (size_t)(r * 64 + rowb) * 1024 + (kt) * 64 + kx,       \
                  (char*)sm[0][buf] + r * 8192 + w * 1024);                   \
      gload_lds16(Bg + (size_t)(r * 64 + rowb) * 1024 + (kt) * 64 + kx,       \
                  (char*)sm[1][buf] + r * 8192 + w * 1024);                   \
    }                                                                         \
  } while (0)

  QKV_STAGE(0, 0);
  QKV_STAGE(1, 1);
  asm volatile("s_waitcnt vmcnt(8)" ::: "memory");   // kt0 landed (kt1 in flight)
  __builtin_amdgcn_s_barrier();
  __builtin_amdgcn_sched_barrier(0);

#pragma unroll 2
  for (int t = 0; t < QKV_NT; ++t) {
    const int cur = t & 1;
    const char* Ab = (const char*)sm[0][cur];
    const char* Bb = (const char*)sm[1][cur];

    bf16x8 av[8], bv[4];
#pragma unroll
    for (int m = 0; m < 8; ++m)
      av[m] = *(const bf16x8*)(Ab + ((wm * 128 + m * 16 + lr) << 7) + cswz0);
#pragma unroll
    for (int n = 0; n < 4; ++n)
      bv[n] = *(const bf16x8*)(Bb + ((wn * 64 + n * 16 + lr) << 7) + cswz0);
#pragma unroll
    for (int m = 0; m < 8; ++m)
#pragma unroll
      for (int n = 0; n < 4; ++n)
        acc[m][n] = __builtin_amdgcn_mfma_f32_16x16x32_bf16(av[m], bv[n], acc[m][n], 0, 0, 0);

    bf16x8 av1[8], bv1[4];
#pragma unroll
    for (int m = 0; m < 8; ++m)
      av1[m] = *(const bf16x8*)(Ab + ((wm * 128 + m * 16 + lr) << 7) + (cswz0 ^ 64));
#pragma unroll
    for (int n = 0; n < 4; ++n)
      bv1[n] = *(const bf16x8*)(Bb + ((wn * 64 + n * 16 + lr) << 7) + (cswz0 ^ 64));

    asm volatile("s_waitcnt lgkmcnt(0)" ::: "memory");  // all cur reads done
    __builtin_amdgcn_s_barrier();
    __builtin_amdgcn_sched_barrier(0);

    if (t + 2 < QKV_NT) QKV_STAGE(cur, t + 2);

    __builtin_amdgcn_s_setprio(1);
#pragma unroll
    for (int m = 0; m < 8; ++m)
#pragma unroll
      for (int n = 0; n < 4; ++n)
        acc[m][n] = __builtin_amdgcn_mfma_f32_16x16x32_bf16(av1[m], bv1[n], acc[m][n], 0, 0, 0);
    __builtin_amdgcn_s_setprio(0);

    if (t + 2 < QKV_NT) {
      asm volatile("s_waitcnt vmcnt(8)" ::: "memory"); // kt t+1 fully landed
    } else {
      asm volatile("s_waitcnt vmcnt(0)" ::: "memory"); // tail drain
    }
    __builtin_amdgcn_s_barrier();
    __builtin_amdgcn_sched_barrier(0);
  }

  // epilogue: C fragment (row = base + (lane>>4)*4 + i, col = base + (lane&15))
  const int cr = lk4 << 2;
  const int z = bn >> 2;                       // 0=Q 1=K 2=V (256 | 1024)
  const int gr0 = bm * 256 + wm * 128;
  const int gc0 = (bn & 3) * 256 + wn * 64;
  if (z < 2) {
    unsigned short* C = (z == 0) ? Q : Kb;
#pragma unroll
    for (int m = 0; m < 8; ++m)
#pragma unroll
      for (int n = 0; n < 4; ++n)
#pragma unroll
        for (int i = 0; i < 4; ++i)
          C[(size_t)(gr0 + m * 16 + cr + i) * 1024 + (gc0 + n * 16 + lr)] =
              f32_to_bf16(acc[m][n][i]);
  } else {
    // Vt[b][d][t] = V[b*512+t][d]; 4 consecutive t per lane -> 8B store
#pragma unroll
    for (int m = 0; m < 8; ++m) {
      const int gr = gr0 + m * 16 + cr;
      const int b = gr >> 9, tt = gr & 511;
#pragma unroll
      for (int n = 0; n < 4; ++n) {
        const int d = gc0 + n * 16 + lr;
        US4 u;
        u.s[0] = f32_to_bf16(acc[m][n][0]);
        u.s[1] = f32_to_bf16(acc[m][n][1]);
        u.s[2] = f32_to_bf16(acc[m][n][2]);
        u.s[3] = f32_to_bf16(acc[m][n][3]);
        *(US4*)(Vt + ((size_t)b * 1024 + d) * 512 + tt) = u;
      }
    }
  }
}

// ---------------- shared BT-GEMM core (m97 structure, 128x128) ----------
__device__ __forceinline__ void gemm_bt_core(const unsigned short* __restrict__ A,
                                             const unsigned short* __restrict__ B,
                                             int lda, int ldb, int K,
                                             unsigned short* As, unsigned short* Bs,
                                             f32x4 acc[4][4]) {
  const int tid = threadIdx.x;
  const int w = tid >> 6, lane = tid & 63;
  const int wr = w >> 1, wc = w & 1;
  const int lr = lane & 15;
  const int lk = (lane >> 4) << 3;

  for (int kk = 0; kk < K; kk += 32) {
#pragma unroll
    for (int j = 0; j < 2; ++j) {
      const int i = (w << 1) + j;            // 0..7 wave-load id
      const int c = (i << 6) + lane;         // 16B chunk id, 512 per tile
      const int r = c >> 2;                  // tile row 0..127
      const int k8 = (c & 3) << 3;           // k offset within BK
      gload_lds16(A + (size_t)r * lda + kk + k8, As + (i << 9));
      gload_lds16(B + (size_t)r * ldb + kk + k8, Bs + (i << 9));
    }
    __syncthreads();                         // drains vmcnt for all waves
    bf16x8 av[4], bv[4];
#pragma unroll
    for (int m = 0; m < 4; ++m)
      av[m] = *(const bf16x8*)(As + (((wr << 6) + (m << 4) + lr) << 5) + lk);
#pragma unroll
    for (int n = 0; n < 4; ++n)
      bv[n] = *(const bf16x8*)(Bs + (((wc << 6) + (n << 4) + lr) << 5) + lk);
#pragma unroll
    for (int m = 0; m < 4; ++m)
#pragma unroll
      for (int n = 0; n < 4; ++n)
        acc[m][n] = __builtin_amdgcn_mfma_f32_16x16x32_bf16(av[m], bv[n], acc[m][n], 0, 0, 0);
    __syncthreads();
  }
}

// ---------------- S = Q K^T per batch (f32 out) ----------------
__global__ __launch_bounds__(256) void s_gemm(const unsigned short* __restrict__ Q,
                                              const unsigned short* __restrict__ Kb,
                                              float* __restrict__ S) {
  __shared__ unsigned short As[4096];
  __shared__ unsigned short Bs[4096];
  const int bn = blockIdx.x, bm = blockIdx.y, b = blockIdx.z;
  const unsigned short* A = Q + ((size_t)b * 512 + bm * 128) * 1024;
  const unsigned short* B = Kb + ((size_t)b * 512 + bn * 128) * 1024;
  f32x4 acc[4][4] = {};
  gemm_bt_core(A, B, 1024, 1024, 1024, As, Bs, acc);

  const int tid = threadIdx.x;
  const int w = tid >> 6, lane = tid & 63;
  const int wr = w >> 1, wc = w & 1;
  const int cr = (lane >> 4) << 2;
  const int cc = lane & 15;
  float* Cp = S + (size_t)b * 262144;
  const int rbase = bm * 128 + wr * 64;
  const int cbase = bn * 128 + wc * 64;
#pragma unroll
  for (int m = 0; m < 4; ++m)
#pragma unroll
    for (int n = 0; n < 4; ++n)
#pragma unroll
      for (int i = 0; i < 4; ++i)
        Cp[(size_t)(rbase + m * 16 + cr + i) * 512 + (cbase + n * 16 + cc)] = acc[m][n][i];
}

// ---------------- row L2-normalize + softmax; write attn f32 + P bf16 -------
__global__ __launch_bounds__(256) void softmax_rows(const float* __restrict__ S,
                                                    float* __restrict__ out,
                                                    unsigned short* __restrict__ P) {
  const int w = threadIdx.x >> 6, lane = threadIdx.x & 63;
  const int r = blockIdx.x * 4 + w;          // global row 0..16383
  const int b = r >> 9, s = r & 511;
  const float4* sp = (const float4*)(S + (size_t)r * 512 + lane * 8);
  float4 a = sp[0], c = sp[1];
  float x[8] = {a.x, a.y, a.z, a.w, c.x, c.y, c.z, c.w};
  float ss = 0.f;
#pragma unroll
  for (int i = 0; i < 8; ++i) ss += x[i] * x[i];
  ss = wave_sum(ss);
  const float inv = 1.0f / fmaxf(sqrtf(ss), 1e-12f);
  float mx = -1e30f;
#pragma unroll
  for (int i = 0; i < 8; ++i) { x[i] *= inv; mx = fmaxf(mx, x[i]); }
  mx = wave_max(mx);
  float se = 0.f;
#pragma unroll
  for (int i = 0; i < 8; ++i) { x[i] = __expf(x[i] - mx); se += x[i]; }
  se = wave_sum(se);
  const float rs = 1.0f / se;
#pragma unroll
  for (int i = 0; i < 8; ++i) x[i] *= rs;

  float* op = out + (size_t)b * 786432 + 524288 + (size_t)s * 512 + lane * 8;
  float4 o0 = {x[0], x[1], x[2], x[3]};
  float4 o1 = {x[4], x[5], x[6], x[7]};
  *(float4*)op = o0;
  *(float4*)(op + 4) = o1;
  US8 u;
#pragma unroll
  for (int i = 0; i < 8; ++i) u.s[i] = f32_to_bf16(x[i]);
  *(US8*)(P + (size_t)r * 512 + lane * 8) = u;
}

// ---------------- O = P * V (via Vt, BT layout), f32 out ----------------
__global__ __launch_bounds__(256) void pv_gemm(const unsigned short* __restrict__ P,
                                               const unsigned short* __restrict__ Vt,
                                               float* __restrict__ O) {
  __shared__ unsigned short As[4096];
  __shared__ unsigned short Bs[4096];
  const int bn = blockIdx.x, bm = blockIdx.y, b = blockIdx.z;
  const unsigned short* A = P + ((size_t)b * 512 + bm * 128) * 512;
  const unsigned short* B = Vt + ((size_t)b * 1024 + bn * 128) * 512;
  f32x4 acc[4][4] = {};
  gemm_bt_core(A, B, 512, 512, 512, As, Bs, acc);

  const int tid = threadIdx.x;
  const int w = tid >> 6, lane = tid & 63;
  const int wr = w >> 1, wc = w & 1;
  const int cr = (lane >> 4) << 2;
  const int cc = lane & 15;
  const int grow = b * 512 + bm * 128 + wr * 64;
  const int cbase = bn * 128 + wc * 64;
#pragma unroll
  for (int m = 0; m < 4; ++m)
#pragma unroll
    for (int n = 0; n < 4; ++n)
#pragma unroll
      for (int i = 0; i < 4; ++i)
        O[(size_t)(grow + m * 16 + cr + i) * 1024 + (cbase + n * 16 + cc)] = acc[m][n][i];
}

// ---------------- residual + LayerNorm, wave per row ----------------
__global__ __launch_bounds__(256) void ln_rows(const float* __restrict__ O,
                                               const float* __restrict__ data,
                                               const float* __restrict__ gamma,
                                               const float* __restrict__ beta,
                                               float* __restrict__ out) {
  const int w = threadIdx.x >> 6, lane = threadIdx.x & 63;
  const int r = blockIdx.x * 4 + w;
  const int b = r >> 9, s = r & 511;
  const float* orow = O + (size_t)r * 1024;
  const float* drow = data + (size_t)r * 1024;
  float x[16];
  float sm = 0.f, sq = 0.f;
#pragma unroll
  for (int j = 0; j < 4; ++j) {
    const int col = j * 256 + lane * 4;
    float4 o4 = *(const float4*)(orow + col);
    float4 d4 = *(const float4*)(drow + col);
    x[j * 4 + 0] = o4.x + d4.x;
    x[j * 4 + 1] = o4.y + d4.y;
    x[j * 4 + 2] = o4.z + d4.z;
    x[j * 4 + 3] = o4.w + d4.w;
  }
#pragma unroll
  for (int i = 0; i < 16; ++i) { sm += x[i]; sq += x[i] * x[i]; }
  sm = wave_sum(sm);
  sq = wave_sum(sq);
  const float mean = sm * (1.0f / 1024.0f);
  const float var = sq * (1.0f / 1024.0f) - mean * mean;
  const float rstd = rsqrtf(var + 1e-6f);
  float* op = out + (size_t)b * 786432 + (size_t)s * 1024;
#pragma unroll
  for (int j = 0; j < 4; ++j) {
    const int col = j * 256 + lane * 4;
    float4 g4 = *(const float4*)(gamma + col);
    float4 b4 = *(const float4*)(beta + col);
    float4 y;
    y.x = (x[j * 4 + 0] - mean) * rstd * g4.x + b4.x;
    y.y = (x[j * 4 + 1] - mean) * rstd * g4.y + b4.y;
    y.z = (x[j * 4 + 2] - mean) * rstd * g4.z + b4.z;
    y.w = (x[j * 4 + 3] - mean) * rstd * g4.w + b4.w;
    *(float4*)(op + col) = y;
  }
}

extern "C" void kernel_launch(void* const* d_in, const int* in_sizes, int n_in,
                              void* d_out, int out_size, void* d_ws, size_t ws_size,
                              hipStream_t stream) {
  const float* data  = (const float*)d_in[0];
  const float* wq    = (const float*)d_in[1];
  const float* wk    = (const float*)d_in[2];
  const float* wv    = (const float*)d_in[3];
  const float* gamma = (const float*)d_in[4];
  const float* beta  = (const float*)d_in[5];
  float* out = (float*)d_out;
  char* ws = (char*)d_ws;
  if (ws_size < WS_NEED) return;

  unsigned short* Xb = (unsigned short*)(ws + WS_XB);
  unsigned short* Wb = (unsigned short*)(ws + WS_WB);
  unsigned short* Q  = (unsigned short*)(ws + WS_Q);
  unsigned short* Kb = (unsigned short*)(ws + WS_K);
  unsigned short* Vt = (unsigned short*)(ws + WS_VT);
  float*          S  = (float*)(ws + WS_S);
  unsigned short* P  = (unsigned short*)(ws + WS_P);
  float*          O  = (float*)(ws + WS_O);

  cvt_f32_bf16<<<8192, 256, 0, stream>>>(data, Xb, 2097152);
  cvt_f32_bf16<<<512, 256, 0, stream>>>(wq, Wb, 131072);
  cvt_f32_bf16<<<512, 256, 0, stream>>>(wk, Wb + 1048576, 131072);
  cvt_f32_bf16<<<512, 256, 0, stream>>>(wv, Wb + 2097152, 131072);
  qkv_gemm256<<<768, 512, 0, stream>>>(Xb, Wb, Q, Kb, Vt);
  s_gemm<<<dim3(4, 4, 32), 256, 0, stream>>>(Q, Kb, S);
  softmax_rows<<<4096, 256, 0, stream>>>(S, out, P);
  pv_gemm<<<dim3(8, 4, 32), 256, 0, stream>>>(P, Vt, O);
  ln_rows<<<4096, 256, 0, stream>>>(O, data, gamma, beta, out);
}

// Round 4
// 242.361 us; speedup vs baseline: 1.6613x; 1.6613x over previous
//
#include <hip/hip_runtime.h>
#include <hip/hip_bf16.h>

// ModalAttention fused pipeline, MI355X (gfx950).
//
// Math: attn/|global_min| followed by L2-normalize cancels any positive
// per-tensor scale (incl. /sqrt(h)) -> softmax input = s_row/||s_row||_2,
// s = q.k. No global-min reduction needed.
//
// Round 4: QKV = 256x256 tile, 4-slot LDS ring of BK=32 subtiles.
// Change vs round 3: NO offset immediate on global_load_lds (semantics
// unverified on gfx950 -> suspected cause of round-3 corruption). Global
// per-lane pointers advance by 64B after each stage instead; offset=0
// always (the round-1-proven configuration).
// Per phase: vmcnt(8); s_barrier; 12 ds_read_b128 consumed immediately by
// 32 MFMA; stage subtile s+3 (4 x global_load_lds). Counted vmcnt
// (8 steady, 8/4/0 tail). BK=32 rows are 64B: each wave ds_read_b128
// covers a contiguous bank-uniform 1KB block -> conflict-free, no swizzle.

typedef __bf16 bf16x8 __attribute__((ext_vector_type(8)));
typedef float f32x4 __attribute__((ext_vector_type(4)));

struct alignas(16) US8 { unsigned short s[8]; };
struct alignas(8)  US4 { unsigned short s[4]; };

// ---------------- workspace layout (bytes) ----------------
#define WS_XB   0ull                        // data bf16  [16384][1024]  33.55MB
#define WS_WB   33554432ull                 // wq,wk,wv bf16 [3][1024][1024] 6.29MB
#define WS_Q    39845888ull                 // Q bf16 [16384][1024] 33.55MB
#define WS_K    73400320ull                 // K bf16 [16384][1024] 33.55MB
#define WS_VT   106954752ull                // V^T bf16 [32][1024][512] 33.55MB
#define WS_S    140509184ull                // S bf16 [16384][512] 16.78MB
#define WS_P    157286400ull                // P bf16 [16384][512] 16.78MB
#define WS_NEED 174063616ull
#define WS_O    WS_Q                        // O bf16 [16384][1024] 33.55MB reuses Q

__device__ __forceinline__ unsigned short f32_to_bf16(float f) {
  unsigned int u = __builtin_bit_cast(unsigned int, f);
  u += 0x7fffu + ((u >> 16) & 1u);            // round-to-nearest-even
  return (unsigned short)(u >> 16);
}
__device__ __forceinline__ float bf16_to_f32(unsigned short h) {
  return __builtin_bit_cast(float, (unsigned int)h << 16);
}

__device__ __forceinline__ void gload_lds16(const void* g, void* lds) {
  __builtin_amdgcn_global_load_lds(
      (const __attribute__((address_space(1))) unsigned int*)g,
      (__attribute__((address_space(3))) unsigned int*)lds, 16, 0, 0);
}

__device__ __forceinline__ float wave_sum(float v) {
#pragma unroll
  for (int off = 32; off > 0; off >>= 1) v += __shfl_xor(v, off);
  return v;
}
__device__ __forceinline__ float wave_max(float v) {
#pragma unroll
  for (int off = 32; off > 0; off >>= 1) v = fmaxf(v, __shfl_xor(v, off));
  return v;
}

// ---------------- f32 -> bf16 cast ----------------
__global__ __launch_bounds__(256) void cvt_f32_bf16(const float* __restrict__ src,
                                                    unsigned short* __restrict__ dst,
                                                    int n8) {
  int i = blockIdx.x * 256 + threadIdx.x;
  if (i >= n8) return;
  const float4* sp = (const float4*)(src + (size_t)i * 8);
  float4 a = sp[0], b = sp[1];
  US8 u;
  u.s[0] = f32_to_bf16(a.x); u.s[1] = f32_to_bf16(a.y);
  u.s[2] = f32_to_bf16(a.z); u.s[3] = f32_to_bf16(a.w);
  u.s[4] = f32_to_bf16(b.x); u.s[5] = f32_to_bf16(b.y);
  u.s[6] = f32_to_bf16(b.z); u.s[7] = f32_to_bf16(b.w);
  *(US8*)(dst + (size_t)i * 8) = u;
}

// ============ QKV: 256x256 tile, 4-slot BK=32 ring, N=3072 ============
// M=16384, K=1024 (32 subtiles). 768 blocks x 512 threads (8 waves, 2Mx4N).
// LDS: 4 slots x (A[256][32] + B[256][32]) bf16 = 128 KiB.
__global__ __launch_bounds__(512, 2) void qkv_ring(
    const unsigned short* __restrict__ Xb, const unsigned short* __restrict__ Wb,
    unsigned short* __restrict__ Q, unsigned short* __restrict__ Kb,
    unsigned short* __restrict__ Vt) {
  __shared__ unsigned short sm[4][16384];   // slot: A bytes [0,16384), B [16384,32768)

  const int tid = threadIdx.x;
  const int w = tid >> 6, lane = tid & 63;
  const int wm = w >> 2, wn = w & 3;
  const int lr = lane & 15, lk4 = lane >> 4;

  // bijective XCD-chunked swizzle: 768 blocks, 96 per XCD
  const int bid = blockIdx.x;
  const int wg = (bid & 7) * 96 + (bid >> 3);
  const int bm = wg / 12, bn = wg % 12;

  const char* Ag = (const char*)(Xb + (size_t)bm * 256 * 1024);
  const char* Bg = (const char*)(Wb + (size_t)bn * 256 * 1024);

  // per-lane stage source: row = {0,128} + w*16 + (lane>>2), 16B chunk = lane&3
  const int srow = w * 16 + (lane >> 2);
  const int schunk = (lane & 3) * 16;
  const char* gA0 = Ag + (size_t)srow * 2048 + schunk;
  const char* gA1 = gA0 + 128 * 2048;
  const char* gB0 = Bg + (size_t)srow * 2048 + schunk;
  const char* gB1 = gB0 + 128 * 2048;

  // read constants
  const int wmbase = wm * 128 + lr;   // A row base (+ m*16)
  const int wnbase = wn * 64 + lr;    // B row base (+ n*16)
  const int rk = lk4 * 16;            // k-byte within 64B row

  f32x4 acc[8][4] = {};

  // stage current k-position into slot SI, then advance pointers by 64B.
  // Stages occur exactly once per subtile in order => pointer == kt*64.
#define QKV_STAGE4(SI)                                                        \
  do {                                                                        \
    char* dA = (char*)sm[SI] + w * 1024;                                      \
    gload_lds16(gA0, dA);                                                     \
    gload_lds16(gA1, dA + 8192);                                              \
    gload_lds16(gB0, dA + 16384);                                             \
    gload_lds16(gB1, dA + 24576);                                             \
    gA0 += 64; gA1 += 64; gB0 += 64; gB1 += 64;                               \
  } while (0)

#define QKV_PHASE(SLOT, VM, DO_STAGE)                                         \
  do {                                                                        \
    asm volatile("s_waitcnt vmcnt(" #VM ")" ::: "memory");                    \
    __builtin_amdgcn_s_barrier();                                             \
    __builtin_amdgcn_sched_barrier(0);                                        \
    const char* sA = (const char*)sm[SLOT];                                   \
    const char* sB = sA + 16384;                                              \
    bf16x8 av[8], bv[4];                                                      \
    _Pragma("unroll") for (int m = 0; m < 8; ++m)                             \
        av[m] = *(const bf16x8*)(sA + ((wmbase + m * 16) << 6) + rk);         \
    _Pragma("unroll") for (int n = 0; n < 4; ++n)                             \
        bv[n] = *(const bf16x8*)(sB + ((wnbase + n * 16) << 6) + rk);         \
    if (DO_STAGE) QKV_STAGE4((SLOT + 3) & 3);                                 \
    __builtin_amdgcn_s_setprio(1);                                            \
    _Pragma("unroll") for (int m = 0; m < 8; ++m)                             \
        _Pragma("unroll") for (int n = 0; n < 4; ++n)                         \
            acc[m][n] = __builtin_amdgcn_mfma_f32_16x16x32_bf16(              \
                av[m], bv[n], acc[m][n], 0, 0, 0);                            \
    __builtin_amdgcn_s_setprio(0);                                            \
    __builtin_amdgcn_sched_barrier(0);                                        \
  } while (0)

  // prologue: stage subtiles 0,1,2 into slots 0,1,2 (12 loads/wave in flight)
  QKV_STAGE4(0);
  QKV_STAGE4(1);
  QKV_STAGE4(2);

  // main: phases s=0..27 (7 iters x 4), each stages subtile s+3
  for (int i = 0; i < 7; ++i) {
    QKV_PHASE(0, 8, 1);
    QKV_PHASE(1, 8, 1);
    QKV_PHASE(2, 8, 1);
    QKV_PHASE(3, 8, 1);
  }
  // tail: s=28 (stages subtile 31), 29, 30, 31
  QKV_PHASE(0, 8, 1);
  QKV_PHASE(1, 8, 0);
  QKV_PHASE(2, 4, 0);
  QKV_PHASE(3, 0, 0);

#undef QKV_PHASE
#undef QKV_STAGE4

  // epilogue: C fragment (row = base + (lane>>4)*4 + i, col = base + (lane&15))
  const int cr = lk4 << 2;
  const int z = bn >> 2;                       // 0=Q 1=K 2=V
  const int gr0 = bm * 256 + wm * 128;
  const int gc0 = (bn & 3) * 256 + wn * 64;
  if (z < 2) {
    unsigned short* C = (z == 0) ? Q : Kb;
#pragma unroll
    for (int m = 0; m < 8; ++m)
#pragma unroll
      for (int n = 0; n < 4; ++n)
#pragma unroll
        for (int i = 0; i < 4; ++i)
          C[(size_t)(gr0 + m * 16 + cr + i) * 1024 + (gc0 + n * 16 + lr)] =
              f32_to_bf16(acc[m][n][i]);
  } else {
    // Vt[b][d][t] = V[b*512+t][d]; 4 consecutive t per lane -> 8B store
#pragma unroll
    for (int m = 0; m < 8; ++m) {
      const int gr = gr0 + m * 16 + cr;
      const int b = gr >> 9, tt = gr & 511;
#pragma unroll
      for (int n = 0; n < 4; ++n) {
        const int d = gc0 + n * 16 + lr;
        US4 u;
        u.s[0] = f32_to_bf16(acc[m][n][0]);
        u.s[1] = f32_to_bf16(acc[m][n][1]);
        u.s[2] = f32_to_bf16(acc[m][n][2]);
        u.s[3] = f32_to_bf16(acc[m][n][3]);
        *(US4*)(Vt + ((size_t)b * 1024 + d) * 512 + tt) = u;
      }
    }
  }
}

// ---------------- shared BT-GEMM core (m97 structure, 128x128) ----------
__device__ __forceinline__ void gemm_bt_core(const unsigned short* __restrict__ A,
                                             const unsigned short* __restrict__ B,
                                             int lda, int ldb, int K,
                                             unsigned short* As, unsigned short* Bs,
                                             f32x4 acc[4][4]) {
  const int tid = threadIdx.x;
  const int w = tid >> 6, lane = tid & 63;
  const int wr = w >> 1, wc = w & 1;
  const int lr = lane & 15;
  const int lk = (lane >> 4) << 3;

  for (int kk = 0; kk < K; kk += 32) {
#pragma unroll
    for (int j = 0; j < 2; ++j) {
      const int i = (w << 1) + j;            // 0..7 wave-load id
      const int c = (i << 6) + lane;         // 16B chunk id, 512 per tile
      const int r = c >> 2;                  // tile row 0..127
      const int k8 = (c & 3) << 3;           // k offset within BK
      gload_lds16(A + (size_t)r * lda + kk + k8, As + (i << 9));
      gload_lds16(B + (size_t)r * ldb + kk + k8, Bs + (i << 9));
    }
    __syncthreads();                         // drains vmcnt for all waves
    bf16x8 av[4], bv[4];
#pragma unroll
    for (int m = 0; m < 4; ++m)
      av[m] = *(const bf16x8*)(As + (((wr << 6) + (m << 4) + lr) << 5) + lk);
#pragma unroll
    for (int n = 0; n < 4; ++n)
      bv[n] = *(const bf16x8*)(Bs + (((wc << 6) + (n << 4) + lr) << 5) + lk);
#pragma unroll
    for (int m = 0; m < 4; ++m)
#pragma unroll
      for (int n = 0; n < 4; ++n)
        acc[m][n] = __builtin_amdgcn_mfma_f32_16x16x32_bf16(av[m], bv[n], acc[m][n], 0, 0, 0);
    __syncthreads();
  }
}

// ---------------- S = Q K^T per batch (bf16 out) ----------------
__global__ __launch_bounds__(256) void s_gemm(const unsigned short* __restrict__ Q,
                                              const unsigned short* __restrict__ Kb,
                                              unsigned short* __restrict__ S) {
  __shared__ unsigned short As[4096];
  __shared__ unsigned short Bs[4096];
  const int bn = blockIdx.x, bm = blockIdx.y, b = blockIdx.z;
  const unsigned short* A = Q + ((size_t)b * 512 + bm * 128) * 1024;
  const unsigned short* B = Kb + ((size_t)b * 512 + bn * 128) * 1024;
  f32x4 acc[4][4] = {};
  gemm_bt_core(A, B, 1024, 1024, 1024, As, Bs, acc);

  const int tid = threadIdx.x;
  const int w = tid >> 6, lane = tid & 63;
  const int wr = w >> 1, wc = w & 1;
  const int cr = (lane >> 4) << 2;
  const int cc = lane & 15;
  unsigned short* Cp = S + (size_t)b * 262144;
  const int rbase = bm * 128 + wr * 64;
  const int cbase = bn * 128 + wc * 64;
#pragma unroll
  for (int m = 0; m < 4; ++m)
#pragma unroll
    for (int n = 0; n < 4; ++n)
#pragma unroll
      for (int i = 0; i < 4; ++i)
        Cp[(size_t)(rbase + m * 16 + cr + i) * 512 + (cbase + n * 16 + cc)] =
            f32_to_bf16(acc[m][n][i]);
}

// ---------------- row L2-normalize + softmax; write attn f32 + P bf16 -------
__global__ __launch_bounds__(256) void softmax_rows(const unsigned short* __restrict__ S,
                                                    float* __restrict__ out,
                                                    unsigned short* __restrict__ P) {
  const int w = threadIdx.x >> 6, lane = threadIdx.x & 63;
  const int r = blockIdx.x * 4 + w;          // global row 0..16383
  const int b = r >> 9, s = r & 511;
  US8 v = *(const US8*)(S + (size_t)r * 512 + lane * 8);
  float x[8];
#pragma unroll
  for (int i = 0; i < 8; ++i) x[i] = bf16_to_f32(v.s[i]);
  float ss = 0.f;
#pragma unroll
  for (int i = 0; i < 8; ++i) ss += x[i] * x[i];
  ss = wave_sum(ss);
  const float inv = 1.0f / fmaxf(sqrtf(ss), 1e-12f);
  float mx = -1e30f;
#pragma unroll
  for (int i = 0; i < 8; ++i) { x[i] *= inv; mx = fmaxf(mx, x[i]); }
  mx = wave_max(mx);
  float se = 0.f;
#pragma unroll
  for (int i = 0; i < 8; ++i) { x[i] = __expf(x[i] - mx); se += x[i]; }
  se = wave_sum(se);
  const float rs = 1.0f / se;
#pragma unroll
  for (int i = 0; i < 8; ++i) x[i] *= rs;

  float* op = out + (size_t)b * 786432 + 524288 + (size_t)s * 512 + lane * 8;
  float4 o0 = {x[0], x[1], x[2], x[3]};
  float4 o1 = {x[4], x[5], x[6], x[7]};
  *(float4*)op = o0;
  *(float4*)(op + 4) = o1;
  US8 u;
#pragma unroll
  for (int i = 0; i < 8; ++i) u.s[i] = f32_to_bf16(x[i]);
  *(US8*)(P + (size_t)r * 512 + lane * 8) = u;
}

// ---------------- O = P * V (via Vt, BT layout), bf16 out ----------------
__global__ __launch_bounds__(256) void pv_gemm(const unsigned short* __restrict__ P,
                                               const unsigned short* __restrict__ Vt,
                                               unsigned short* __restrict__ O) {
  __shared__ unsigned short As[4096];
  __shared__ unsigned short Bs[4096];
  const int bn = blockIdx.x, bm = blockIdx.y, b = blockIdx.z;
  const unsigned short* A = P + ((size_t)b * 512 + bm * 128) * 512;
  const unsigned short* B = Vt + ((size_t)b * 1024 + bn * 128) * 512;
  f32x4 acc[4][4] = {};
  gemm_bt_core(A, B, 512, 512, 512, As, Bs, acc);

  const int tid = threadIdx.x;
  const int w = tid >> 6, lane = tid & 63;
  const int wr = w >> 1, wc = w & 1;
  const int cr = (lane >> 4) << 2;
  const int cc = lane & 15;
  const int grow = b * 512 + bm * 128 + wr * 64;
  const int cbase = bn * 128 + wc * 64;
#pragma unroll
  for (int m = 0; m < 4; ++m)
#pragma unroll
    for (int n = 0; n < 4; ++n)
#pragma unroll
      for (int i = 0; i < 4; ++i)
        O[(size_t)(grow + m * 16 + cr + i) * 1024 + (cbase + n * 16 + cc)] =
            f32_to_bf16(acc[m][n][i]);
}

// ---------------- residual + LayerNorm, wave per row ----------------
__global__ __launch_bounds__(256) void ln_rows(const unsigned short* __restrict__ O,
                                               const float* __restrict__ data,
                                               const float* __restrict__ gamma,
                                               const float* __restrict__ beta,
                                               float* __restrict__ out) {
  const int w = threadIdx.x >> 6, lane = threadIdx.x & 63;
  const int r = blockIdx.x * 4 + w;
  const int b = r >> 9, s = r & 511;
  const unsigned short* orow = O + (size_t)r * 1024;
  const float* drow = data + (size_t)r * 1024;
  float x[16];
  float sm = 0.f, sq = 0.f;
#pragma unroll
  for (int j = 0; j < 4; ++j) {
    const int col = j * 256 + lane * 4;
    US4 o4 = *(const US4*)(orow + col);
    float4 d4 = *(const float4*)(drow + col);
    x[j * 4 + 0] = bf16_to_f32(o4.s[0]) + d4.x;
    x[j * 4 + 1] = bf16_to_f32(o4.s[1]) + d4.y;
    x[j * 4 + 2] = bf16_to_f32(o4.s[2]) + d4.z;
    x[j * 4 + 3] = bf16_to_f32(o4.s[3]) + d4.w;
  }
#pragma unroll
  for (int i = 0; i < 16; ++i) { sm += x[i]; sq += x[i] * x[i]; }
  sm = wave_sum(sm);
  sq = wave_sum(sq);
  const float mean = sm * (1.0f / 1024.0f);
  const float var = sq * (1.0f / 1024.0f) - mean * mean;
  const float rstd = rsqrtf(var + 1e-6f);
  float* op = out + (size_t)b * 786432 + (size_t)s * 1024;
#pragma unroll
  for (int j = 0; j < 4; ++j) {
    const int col = j * 256 + lane * 4;
    float4 g4 = *(const float4*)(gamma + col);
    float4 b4 = *(const float4*)(beta + col);
    float4 y;
    y.x = (x[j * 4 + 0] - mean) * rstd * g4.x + b4.x;
    y.y = (x[j * 4 + 1] - mean) * rstd * g4.y + b4.y;
    y.z = (x[j * 4 + 2] - mean) * rstd * g4.z + b4.z;
    y.w = (x[j * 4 + 3] - mean) * rstd * g4.w + b4.w;
    *(float4*)(op + col) = y;
  }
}

extern "C" void kernel_launch(void* const* d_in, const int* in_sizes, int n_in,
                              void* d_out, int out_size, void* d_ws, size_t ws_size,
                              hipStream_t stream) {
  const float* data  = (const float*)d_in[0];
  const float* wq    = (const float*)d_in[1];
  const float* wk    = (const float*)d_in[2];
  const float* wv    = (const float*)d_in[3];
  const float* gamma = (const float*)d_in[4];
  const float* beta  = (const float*)d_in[5];
  float* out = (float*)d_out;
  char* ws = (char*)d_ws;
  if (ws_size < WS_NEED) return;

  unsigned short* Xb = (unsigned short*)(ws + WS_XB);
  unsigned short* Wb = (unsigned short*)(ws + WS_WB);
  unsigned short* Q  = (unsigned short*)(ws + WS_Q);
  unsigned short* Kb = (unsigned short*)(ws + WS_K);
  unsigned short* Vt = (unsigned short*)(ws + WS_VT);
  unsigned short* S  = (unsigned short*)(ws + WS_S);
  unsigned short* P  = (unsigned short*)(ws + WS_P);
  unsigned short* O  = (unsigned short*)(ws + WS_O);

  cvt_f32_bf16<<<8192, 256, 0, stream>>>(data, Xb, 2097152);
  cvt_f32_bf16<<<512, 256, 0, stream>>>(wq, Wb, 131072);
  cvt_f32_bf16<<<512, 256, 0, stream>>>(wk, Wb + 1048576, 131072);
  cvt_f32_bf16<<<512, 256, 0, stream>>>(wv, Wb + 2097152, 131072);
  qkv_ring<<<768, 512, 0, stream>>>(Xb, Wb, Q, Kb, Vt);
  s_gemm<<<dim3(4, 4, 32), 256, 0, stream>>>(Q, Kb, S);
  softmax_rows<<<4096, 256, 0, stream>>>(S, out, P);
  pv_gemm<<<dim3(8, 4, 32), 256, 0, stream>>>(P, Vt, O);
  ln_rows<<<4096, 256, 0, stream>>>(O, data, gamma, beta, out);
}

// Round 5
// 238.335 us; speedup vs baseline: 1.6894x; 1.0169x over previous
//
#include <hip/hip_runtime.h>
#include <hip/hip_bf16.h>

// ModalAttention fused pipeline, MI355X (gfx950).
//
// Math: attn/|global_min| followed by L2-normalize cancels any positive
// per-tensor scale (incl. /sqrt(h)) -> softmax input = s_row/||s_row||_2,
// s = q.k. No global-min reduction needed.
//
// Round 5: two-constant XOR bank swizzle (chunk' = chunk ^ ((row>>1)&3))
// applied to qkv_ring and gemm_bt_core LDS tiles. Round-4 fragment reads
// were 8-way bank conflicted (16 rows @ same 16B col, 64B row stride ->
// bank=(r&1)*16+4*chunk). Swizzle spreads 16 rows over all 8 bank-quads
// -> 2 lanes/bank = free. Stage side: same XOR folded into the per-lane
// global source offset (linear LDS dest, rule 21 both-sides involution).
// Schedule identical to round 4 (4-slot BK=32 ring, counted vmcnt).

typedef __bf16 bf16x8 __attribute__((ext_vector_type(8)));
typedef float f32x4 __attribute__((ext_vector_type(4)));

struct alignas(16) US8 { unsigned short s[8]; };
struct alignas(8)  US4 { unsigned short s[4]; };

// ---------------- workspace layout (bytes) ----------------
#define WS_XB   0ull                        // data bf16  [16384][1024]  33.55MB
#define WS_WB   33554432ull                 // wq,wk,wv bf16 [3][1024][1024] 6.29MB
#define WS_Q    39845888ull                 // Q bf16 [16384][1024] 33.55MB
#define WS_K    73400320ull                 // K bf16 [16384][1024] 33.55MB
#define WS_VT   106954752ull                // V^T bf16 [32][1024][512] 33.55MB
#define WS_S    140509184ull                // S bf16 [16384][512] 16.78MB
#define WS_P    157286400ull                // P bf16 [16384][512] 16.78MB
#define WS_NEED 174063616ull
#define WS_O    WS_Q                        // O bf16 [16384][1024] 33.55MB reuses Q

__device__ __forceinline__ unsigned short f32_to_bf16(float f) {
  unsigned int u = __builtin_bit_cast(unsigned int, f);
  u += 0x7fffu + ((u >> 16) & 1u);            // round-to-nearest-even
  return (unsigned short)(u >> 16);
}
__device__ __forceinline__ float bf16_to_f32(unsigned short h) {
  return __builtin_bit_cast(float, (unsigned int)h << 16);
}

__device__ __forceinline__ void gload_lds16(const void* g, void* lds) {
  __builtin_amdgcn_global_load_lds(
      (const __attribute__((address_space(1))) unsigned int*)g,
      (__attribute__((address_space(3))) unsigned int*)lds, 16, 0, 0);
}

__device__ __forceinline__ float wave_sum(float v) {
#pragma unroll
  for (int off = 32; off > 0; off >>= 1) v += __shfl_xor(v, off);
  return v;
}
__device__ __forceinline__ float wave_max(float v) {
#pragma unroll
  for (int off = 32; off > 0; off >>= 1) v = fmaxf(v, __shfl_xor(v, off));
  return v;
}

// ---------------- f32 -> bf16 cast ----------------
__global__ __launch_bounds__(256) void cvt_f32_bf16(const float* __restrict__ src,
                                                    unsigned short* __restrict__ dst,
                                                    int n8) {
  int i = blockIdx.x * 256 + threadIdx.x;
  if (i >= n8) return;
  const float4* sp = (const float4*)(src + (size_t)i * 8);
  float4 a = sp[0], b = sp[1];
  US8 u;
  u.s[0] = f32_to_bf16(a.x); u.s[1] = f32_to_bf16(a.y);
  u.s[2] = f32_to_bf16(a.z); u.s[3] = f32_to_bf16(a.w);
  u.s[4] = f32_to_bf16(b.x); u.s[5] = f32_to_bf16(b.y);
  u.s[6] = f32_to_bf16(b.z); u.s[7] = f32_to_bf16(b.w);
  *(US8*)(dst + (size_t)i * 8) = u;
}

// ============ QKV: 256x256 tile, 4-slot BK=32 ring, N=3072 ============
// M=16384, K=1024 (32 subtiles). 768 blocks x 512 threads (8 waves, 2Mx4N).
// LDS: 4 slots x (A[256][32] + B[256][32]) bf16 = 128 KiB, XOR-swizzled:
//   LDS chunk' = src chunk ^ ((row>>1)&3)  (16B chunks, 4 per 64B row)
__global__ __launch_bounds__(512, 2) void qkv_ring(
    const unsigned short* __restrict__ Xb, const unsigned short* __restrict__ Wb,
    unsigned short* __restrict__ Q, unsigned short* __restrict__ Kb,
    unsigned short* __restrict__ Vt) {
  __shared__ unsigned short sm[4][16384];   // slot: A bytes [0,16384), B [16384,32768)

  const int tid = threadIdx.x;
  const int w = tid >> 6, lane = tid & 63;
  const int wm = w >> 2, wn = w & 3;
  const int lr = lane & 15, lk4 = lane >> 4;

  // bijective XCD-chunked swizzle: 768 blocks, 96 per XCD
  const int bid = blockIdx.x;
  const int wg = (bid & 7) * 96 + (bid >> 3);
  const int bm = wg / 12, bn = wg % 12;

  const char* Ag = (const char*)(Xb + (size_t)bm * 256 * 1024);
  const char* Bg = (const char*)(Wb + (size_t)bn * 256 * 1024);

  // stage: dest chunk id c = tid + j*512 -> row r=(tid>>2)+j*128, chunk'=tid&3.
  // source chunk = chunk' ^ ((r>>1)&3) = (lane&3) ^ ((lane>>3)&3) (fixed/lane)
  const int srow = w * 16 + (lane >> 2);
  const int schunk = ((lane & 3) ^ ((lane >> 3) & 3)) * 16;
  const char* gA0 = Ag + (size_t)srow * 2048 + schunk;
  const char* gA1 = gA0 + 128 * 2048;
  const char* gB0 = Bg + (size_t)srow * 2048 + schunk;
  const char* gB1 = gB0 + 128 * 2048;

  // read: row = base + lr (base components = 0 mod 8), need src chunk lk4
  //   -> LDS chunk = lk4 ^ ((row>>1)&3) = lk4 ^ ((lr>>1)&3)
  const int wmbase = wm * 128 + lr;   // A row base (+ m*16)
  const int wnbase = wn * 64 + lr;    // B row base (+ n*16)
  const int rk = (lk4 ^ ((lr >> 1) & 3)) * 16;  // swizzled k-byte in 64B row

  f32x4 acc[8][4] = {};

  // stage current k-position into slot SI, then advance pointers by 64B.
#define QKV_STAGE4(SI)                                                        \
  do {                                                                        \
    char* dA = (char*)sm[SI] + w * 1024;                                      \
    gload_lds16(gA0, dA);                                                     \
    gload_lds16(gA1, dA + 8192);                                              \
    gload_lds16(gB0, dA + 16384);                                             \
    gload_lds16(gB1, dA + 24576);                                             \
    gA0 += 64; gA1 += 64; gB0 += 64; gB1 += 64;                               \
  } while (0)

#define QKV_PHASE(SLOT, VM, DO_STAGE)                                         \
  do {                                                                        \
    asm volatile("s_waitcnt vmcnt(" #VM ")" ::: "memory");                    \
    __builtin_amdgcn_s_barrier();                                             \
    __builtin_amdgcn_sched_barrier(0);                                        \
    const char* sA = (const char*)sm[SLOT];                                   \
    const char* sB = sA + 16384;                                              \
    bf16x8 av[8], bv[4];                                                      \
    _Pragma("unroll") for (int m = 0; m < 8; ++m)                             \
        av[m] = *(const bf16x8*)(sA + ((wmbase + m * 16) << 6) + rk);         \
    _Pragma("unroll") for (int n = 0; n < 4; ++n)                             \
        bv[n] = *(const bf16x8*)(sB + ((wnbase + n * 16) << 6) + rk);         \
    if (DO_STAGE) QKV_STAGE4((SLOT + 3) & 3);                                 \
    __builtin_amdgcn_s_setprio(1);                                            \
    _Pragma("unroll") for (int m = 0; m < 8; ++m)                             \
        _Pragma("unroll") for (int n = 0; n < 4; ++n)                         \
            acc[m][n] = __builtin_amdgcn_mfma_f32_16x16x32_bf16(              \
                av[m], bv[n], acc[m][n], 0, 0, 0);                            \
    __builtin_amdgcn_s_setprio(0);                                            \
    __builtin_amdgcn_sched_barrier(0);                                        \
  } while (0)

  // prologue: stage subtiles 0,1,2 into slots 0,1,2 (12 loads/wave in flight)
  QKV_STAGE4(0);
  QKV_STAGE4(1);
  QKV_STAGE4(2);

  // main: phases s=0..27 (7 iters x 4), each stages subtile s+3
  for (int i = 0; i < 7; ++i) {
    QKV_PHASE(0, 8, 1);
    QKV_PHASE(1, 8, 1);
    QKV_PHASE(2, 8, 1);
    QKV_PHASE(3, 8, 1);
  }
  // tail: s=28 (stages subtile 31), 29, 30, 31
  QKV_PHASE(0, 8, 1);
  QKV_PHASE(1, 8, 0);
  QKV_PHASE(2, 4, 0);
  QKV_PHASE(3, 0, 0);

#undef QKV_PHASE
#undef QKV_STAGE4

  // epilogue: C fragment (row = base + (lane>>4)*4 + i, col = base + (lane&15))
  const int cr = lk4 << 2;
  const int z = bn >> 2;                       // 0=Q 1=K 2=V
  const int gr0 = bm * 256 + wm * 128;
  const int gc0 = (bn & 3) * 256 + wn * 64;
  if (z < 2) {
    unsigned short* C = (z == 0) ? Q : Kb;
#pragma unroll
    for (int m = 0; m < 8; ++m)
#pragma unroll
      for (int n = 0; n < 4; ++n)
#pragma unroll
        for (int i = 0; i < 4; ++i)
          C[(size_t)(gr0 + m * 16 + cr + i) * 1024 + (gc0 + n * 16 + lr)] =
              f32_to_bf16(acc[m][n][i]);
  } else {
    // Vt[b][d][t] = V[b*512+t][d]; 4 consecutive t per lane -> 8B store
#pragma unroll
    for (int m = 0; m < 8; ++m) {
      const int gr = gr0 + m * 16 + cr;
      const int b = gr >> 9, tt = gr & 511;
#pragma unroll
      for (int n = 0; n < 4; ++n) {
        const int d = gc0 + n * 16 + lr;
        US4 u;
        u.s[0] = f32_to_bf16(acc[m][n][0]);
        u.s[1] = f32_to_bf16(acc[m][n][1]);
        u.s[2] = f32_to_bf16(acc[m][n][2]);
        u.s[3] = f32_to_bf16(acc[m][n][3]);
        *(US4*)(Vt + ((size_t)b * 1024 + d) * 512 + tt) = u;
      }
    }
  }
}

// ---------------- shared BT-GEMM core (m97 structure + XOR swizzle) ----------
__device__ __forceinline__ void gemm_bt_core(const unsigned short* __restrict__ A,
                                             const unsigned short* __restrict__ B,
                                             int lda, int ldb, int K,
                                             unsigned short* As, unsigned short* Bs,
                                             f32x4 acc[4][4]) {
  const int tid = threadIdx.x;
  const int w = tid >> 6, lane = tid & 63;
  const int wr = w >> 1, wc = w & 1;
  const int lr = lane & 15;
  // read: src chunk (lane>>4) at row base+lr -> LDS chunk ^ ((lr>>1)&3)
  const int lk = (((lane >> 4) ^ ((lr >> 1) & 3))) << 3;
  // stage: dest chunk id c=(i<<6)+lane -> row i*16+(lane>>2), chunk'=lane&3;
  // source chunk = (lane&3) ^ ((lane>>3)&3)
  const int k8 = (((lane & 3) ^ ((lane >> 3) & 3))) << 3;

  for (int kk = 0; kk < K; kk += 32) {
#pragma unroll
    for (int j = 0; j < 2; ++j) {
      const int i = (w << 1) + j;            // 0..7 wave-load id
      const int c = (i << 6) + lane;         // 16B chunk id, 512 per tile
      const int r = c >> 2;                  // tile row 0..127
      gload_lds16(A + (size_t)r * lda + kk + k8, As + (i << 9));
      gload_lds16(B + (size_t)r * ldb + kk + k8, Bs + (i << 9));
    }
    __syncthreads();                         // drains vmcnt for all waves
    bf16x8 av[4], bv[4];
#pragma unroll
    for (int m = 0; m < 4; ++m)
      av[m] = *(const bf16x8*)(As + (((wr << 6) + (m << 4) + lr) << 5) + lk);
#pragma unroll
    for (int n = 0; n < 4; ++n)
      bv[n] = *(const bf16x8*)(Bs + (((wc << 6) + (n << 4) + lr) << 5) + lk);
#pragma unroll
    for (int m = 0; m < 4; ++m)
#pragma unroll
      for (int n = 0; n < 4; ++n)
        acc[m][n] = __builtin_amdgcn_mfma_f32_16x16x32_bf16(av[m], bv[n], acc[m][n], 0, 0, 0);
    __syncthreads();
  }
}

// ---------------- S = Q K^T per batch (bf16 out) ----------------
__global__ __launch_bounds__(256) void s_gemm(const unsigned short* __restrict__ Q,
                                              const unsigned short* __restrict__ Kb,
                                              unsigned short* __restrict__ S) {
  __shared__ unsigned short As[4096];
  __shared__ unsigned short Bs[4096];
  const int bn = blockIdx.x, bm = blockIdx.y, b = blockIdx.z;
  const unsigned short* A = Q + ((size_t)b * 512 + bm * 128) * 1024;
  const unsigned short* B = Kb + ((size_t)b * 512 + bn * 128) * 1024;
  f32x4 acc[4][4] = {};
  gemm_bt_core(A, B, 1024, 1024, 1024, As, Bs, acc);

  const int tid = threadIdx.x;
  const int w = tid >> 6, lane = tid & 63;
  const int wr = w >> 1, wc = w & 1;
  const int cr = (lane >> 4) << 2;
  const int cc = lane & 15;
  unsigned short* Cp = S + (size_t)b * 262144;
  const int rbase = bm * 128 + wr * 64;
  const int cbase = bn * 128 + wc * 64;
#pragma unroll
  for (int m = 0; m < 4; ++m)
#pragma unroll
    for (int n = 0; n < 4; ++n)
#pragma unroll
      for (int i = 0; i < 4; ++i)
        Cp[(size_t)(rbase + m * 16 + cr + i) * 512 + (cbase + n * 16 + cc)] =
            f32_to_bf16(acc[m][n][i]);
}

// ---------------- row L2-normalize + softmax; write attn f32 + P bf16 -------
__global__ __launch_bounds__(256) void softmax_rows(const unsigned short* __restrict__ S,
                                                    float* __restrict__ out,
                                                    unsigned short* __restrict__ P) {
  const int w = threadIdx.x >> 6, lane = threadIdx.x & 63;
  const int r = blockIdx.x * 4 + w;          // global row 0..16383
  const int b = r >> 9, s = r & 511;
  US8 v = *(const US8*)(S + (size_t)r * 512 + lane * 8);
  float x[8];
#pragma unroll
  for (int i = 0; i < 8; ++i) x[i] = bf16_to_f32(v.s[i]);
  float ss = 0.f;
#pragma unroll
  for (int i = 0; i < 8; ++i) ss += x[i] * x[i];
  ss = wave_sum(ss);
  const float inv = 1.0f / fmaxf(sqrtf(ss), 1e-12f);
  float mx = -1e30f;
#pragma unroll
  for (int i = 0; i < 8; ++i) { x[i] *= inv; mx = fmaxf(mx, x[i]); }
  mx = wave_max(mx);
  float se = 0.f;
#pragma unroll
  for (int i = 0; i < 8; ++i) { x[i] = __expf(x[i] - mx); se += x[i]; }
  se = wave_sum(se);
  const float rs = 1.0f / se;
#pragma unroll
  for (int i = 0; i < 8; ++i) x[i] *= rs;

  float* op = out + (size_t)b * 786432 + 524288 + (size_t)s * 512 + lane * 8;
  float4 o0 = {x[0], x[1], x[2], x[3]};
  float4 o1 = {x[4], x[5], x[6], x[7]};
  *(float4*)op = o0;
  *(float4*)(op + 4) = o1;
  US8 u;
#pragma unroll
  for (int i = 0; i < 8; ++i) u.s[i] = f32_to_bf16(x[i]);
  *(US8*)(P + (size_t)r * 512 + lane * 8) = u;
}

// ---------------- O = P * V (via Vt, BT layout), bf16 out ----------------
__global__ __launch_bounds__(256) void pv_gemm(const unsigned short* __restrict__ P,
                                               const unsigned short* __restrict__ Vt,
                                               unsigned short* __restrict__ O) {
  __shared__ unsigned short As[4096];
  __shared__ unsigned short Bs[4096];
  const int bn = blockIdx.x, bm = blockIdx.y, b = blockIdx.z;
  const unsigned short* A = P + ((size_t)b * 512 + bm * 128) * 512;
  const unsigned short* B = Vt + ((size_t)b * 1024 + bn * 128) * 512;
  f32x4 acc[4][4] = {};
  gemm_bt_core(A, B, 512, 512, 512, As, Bs, acc);

  const int tid = threadIdx.x;
  const int w = tid >> 6, lane = tid & 63;
  const int wr = w >> 1, wc = w & 1;
  const int cr = (lane >> 4) << 2;
  const int cc = lane & 15;
  const int grow = b * 512 + bm * 128 + wr * 64;
  const int cbase = bn * 128 + wc * 64;
#pragma unroll
  for (int m = 0; m < 4; ++m)
#pragma unroll
    for (int n = 0; n < 4; ++n)
#pragma unroll
      for (int i = 0; i < 4; ++i)
        O[(size_t)(grow + m * 16 + cr + i) * 1024 + (cbase + n * 16 + cc)] =
            f32_to_bf16(acc[m][n][i]);
}

// ---------------- residual + LayerNorm, wave per row ----------------
__global__ __launch_bounds__(256) void ln_rows(const unsigned short* __restrict__ O,
                                               const float* __restrict__ data,
                                               const float* __restrict__ gamma,
                                               const float* __restrict__ beta,
                                               float* __restrict__ out) {
  const int w = threadIdx.x >> 6, lane = threadIdx.x & 63;
  const int r = blockIdx.x * 4 + w;
  const int b = r >> 9, s = r & 511;
  const unsigned short* orow = O + (size_t)r * 1024;
  const float* drow = data + (size_t)r * 1024;
  float x[16];
  float sm = 0.f, sq = 0.f;
#pragma unroll
  for (int j = 0; j < 4; ++j) {
    const int col = j * 256 + lane * 4;
    US4 o4 = *(const US4*)(orow + col);
    float4 d4 = *(const float4*)(drow + col);
    x[j * 4 + 0] = bf16_to_f32(o4.s[0]) + d4.x;
    x[j * 4 + 1] = bf16_to_f32(o4.s[1]) + d4.y;
    x[j * 4 + 2] = bf16_to_f32(o4.s[2]) + d4.z;
    x[j * 4 + 3] = bf16_to_f32(o4.s[3]) + d4.w;
  }
#pragma unroll
  for (int i = 0; i < 16; ++i) { sm += x[i]; sq += x[i] * x[i]; }
  sm = wave_sum(sm);
  sq = wave_sum(sq);
  const float mean = sm * (1.0f / 1024.0f);
  const float var = sq * (1.0f / 1024.0f) - mean * mean;
  const float rstd = rsqrtf(var + 1e-6f);
  float* op = out + (size_t)b * 786432 + (size_t)s * 1024;
#pragma unroll
  for (int j = 0; j < 4; ++j) {
    const int col = j * 256 + lane * 4;
    float4 g4 = *(const float4*)(gamma + col);
    float4 b4 = *(const float4*)(beta + col);
    float4 y;
    y.x = (x[j * 4 + 0] - mean) * rstd * g4.x + b4.x;
    y.y = (x[j * 4 + 1] - mean) * rstd * g4.y + b4.y;
    y.z = (x[j * 4 + 2] - mean) * rstd * g4.z + b4.z;
    y.w = (x[j * 4 + 3] - mean) * rstd * g4.w + b4.w;
    *(float4*)(op + col) = y;
  }
}

extern "C" void kernel_launch(void* const* d_in, const int* in_sizes, int n_in,
                              void* d_out, int out_size, void* d_ws, size_t ws_size,
                              hipStream_t stream) {
  const float* data  = (const float*)d_in[0];
  const float* wq    = (const float*)d_in[1];
  const float* wk    = (const float*)d_in[2];
  const float* wv    = (const float*)d_in[3];
  const float* gamma = (const float*)d_in[4];
  const float* beta  = (const float*)d_in[5];
  float* out = (float*)d_out;
  char* ws = (char*)d_ws;
  if (ws_size < WS_NEED) return;

  unsigned short* Xb = (unsigned short*)(ws + WS_XB);
  unsigned short* Wb = (unsigned short*)(ws + WS_WB);
  unsigned short* Q  = (unsigned short*)(ws + WS_Q);
  unsigned short* Kb = (unsigned short*)(ws + WS_K);
  unsigned short* Vt = (unsigned short*)(ws + WS_VT);
  unsigned short* S  = (unsigned short*)(ws + WS_S);
  unsigned short* P  = (unsigned short*)(ws + WS_P);
  unsigned short* O  = (unsigned short*)(ws + WS_O);

  cvt_f32_bf16<<<8192, 256, 0, stream>>>(data, Xb, 2097152);
  cvt_f32_bf16<<<512, 256, 0, stream>>>(wq, Wb, 131072);
  cvt_f32_bf16<<<512, 256, 0, stream>>>(wk, Wb + 1048576, 131072);
  cvt_f32_bf16<<<512, 256, 0, stream>>>(wv, Wb + 2097152, 131072);
  qkv_ring<<<768, 512, 0, stream>>>(Xb, Wb, Q, Kb, Vt);
  s_gemm<<<dim3(4, 4, 32), 256, 0, stream>>>(Q, Kb, S);
  softmax_rows<<<4096, 256, 0, stream>>>(S, out, P);
  pv_gemm<<<dim3(8, 4, 32), 256, 0, stream>>>(P, Vt, O);
  ln_rows<<<4096, 256, 0, stream>>>(O, data, gamma, beta, out);
}